// Round 12
// baseline (11821.963 us; speedup 1.0000x reference)
//
#include <hip/hip_runtime.h>

// LSTM_65859028517106 — round 12: 8-wave (512-thread) layer blocks, wave-private
// N=16 slices; per-wave flags, no per-step barriers, direct coalesced h stores.
// Probes whether the bypass-stream limit is per-wave-outstanding (2x win) or
// per-CU (wash). k-major h ring from r11 retained.

typedef short s16x8 __attribute__((ext_vector_type(8)));
typedef float f32x4 __attribute__((ext_vector_type(4)));
typedef int   i32x4 __attribute__((ext_vector_type(4)));

#define NB   128
#define TT   1024
#define HID2 512
#define RING 16
#define RINGM 15
#define NBH  (NB * HID2)

__device__ __forceinline__ unsigned short f2bf(float f) {
  union { float f; unsigned int u; } c; c.f = f;
  return (unsigned short)((c.u + 0x7fffu + ((c.u >> 16) & 1u)) >> 16);
}
__device__ __forceinline__ float sigm(float x) { return 1.0f / (1.0f + __expf(-x)); }
__device__ __forceinline__ float tanhfast(float x) {
  x = fminf(fmaxf(x, -15.0f), 15.0f);
  const float e = __expf(2.0f * x);
  return (e - 1.0f) / (e + 1.0f);
}

__global__ void convW(const float* __restrict__ Wih, const float* __restrict__ Whh,
                      const float* __restrict__ bih, const float* __restrict__ bhh,
                      unsigned short* __restrict__ Wd, float* __restrict__ biasd,
                      const int Kih, const int Khh) {
  const int K = Kih + Khh;
  const int total = 2048 * K;
  for (int idx = blockIdx.x * blockDim.x + threadIdx.x; idx < total;
       idx += gridDim.x * blockDim.x) {
    const int rp = idx / K;
    const int cc = idx - rp * K;
    const int g = rp & 3, u = rp >> 2;
    const int ro = g * 512 + u;
    const float v = (cc < Kih) ? Wih[ro * Kih + cc] : Whh[ro * Khh + (cc - Kih)];
    Wd[idx] = f2bf(v);
    if (cc == 0) biasd[rp] = bih[ro] + bhh[ro];
  }
}

__global__ void convO(const float* __restrict__ Wout, unsigned short* __restrict__ Wd) {
  for (int idx = blockIdx.x * blockDim.x + threadIdx.x; idx < 128 * 512;
       idx += gridDim.x * blockDim.x)
    Wd[idx] = f2bf(Wout[idx]);
}

#define GLD1P(D, P)                                                       \
  asm volatile("global_load_dwordx4 %0, %1, off sc0 sc1"                  \
               : "=v"(D) : "v"(P));
#define BW1(D, VM)                                                        \
  asm volatile("s_waitcnt vmcnt(" VM ")" : "+v"(D)::"memory");

#define MFM(A, B, C) __builtin_amdgcn_mfma_f32_16x16x32_bf16(A, B, C, 0, 0, 0)
#define LDSA(MFi, AK) \
  (*reinterpret_cast<const s16x8*>(smem + (((MFi) * nkit + (AK)) << 10) + lane * 16))

#define C8(S, AK, VM)                                                           \
  {                                                                             \
    BW1(bq[S], VM);                                                             \
    const s16x8 a0 = LDSA(0, AK), a1 = LDSA(1, AK), a2 = LDSA(2, AK),           \
                a3 = LDSA(3, AK);                                               \
    acc[0] = MFM(a0, bq[S], acc[0]);                                            \
    acc[1] = MFM(a1, bq[S], acc[1]);                                            \
    acc[2] = MFM(a2, bq[S], acc[2]);                                            \
    acc[3] = MFM(a3, bq[S], acc[3]);                                            \
  }

#define ISSUE16(BASE, P)                                                        \
  GLD1P(bq[(BASE) + 0], (P))            GLD1P(bq[(BASE) + 1], (P) + 4096)       \
  GLD1P(bq[(BASE) + 2], (P) + 8192)     GLD1P(bq[(BASE) + 3], (P) + 12288)      \
  GLD1P(bq[(BASE) + 4], (P) + 16384)    GLD1P(bq[(BASE) + 5], (P) + 20480)      \
  GLD1P(bq[(BASE) + 6], (P) + 24576)    GLD1P(bq[(BASE) + 7], (P) + 28672)      \
  GLD1P(bq[(BASE) + 8], (P) + 32768)    GLD1P(bq[(BASE) + 9], (P) + 36864)      \
  GLD1P(bq[(BASE) + 10], (P) + 40960)   GLD1P(bq[(BASE) + 11], (P) + 45056)     \
  GLD1P(bq[(BASE) + 12], (P) + 49152)   GLD1P(bq[(BASE) + 13], (P) + 53248)     \
  GLD1P(bq[(BASE) + 14], (P) + 57344)   GLD1P(bq[(BASE) + 15], (P) + 61440)

#define FLG(L, T) (flags + ((size_t)((L) * TT + (T)) << 8))

__global__ __launch_bounds__(512, 2) void lstm_w8(
    const float* __restrict__ x,
    const unsigned short* __restrict__ W0, const unsigned short* __restrict__ W1,
    const unsigned short* __restrict__ W2, const unsigned short* __restrict__ W3,
    const unsigned short* __restrict__ W4,
    const unsigned short* __restrict__ Woutb,
    const float* __restrict__ bias,
    unsigned short* __restrict__ hring,   // [5][RING][64 kc][128 b][8] bf16
    unsigned int* __restrict__ flags,     // [6][TT][256] per-wave flags
    const float* __restrict__ boutp,
    float* __restrict__ outp)
{
  extern __shared__ char smem[];
  const int tid = threadIdx.x;
  const int lane = tid & 63;
  const int w = tid >> 6;          // 0..7
  const int l15 = lane & 15;
  const int l4 = lane >> 4;
  const int bid = blockIdx.x;

  auto poll2 = [&](const unsigned int* pa, const unsigned int* pb) {
    for (;;) {
      i32x4 va, vb;
      asm volatile("global_load_dwordx4 %0, %2, off sc0 sc1\n\t"
                   "global_load_dwordx4 %1, %3, off sc0 sc1\n\t"
                   "s_waitcnt vmcnt(0)"
                   : "=v"(va), "=v"(vb) : "v"(pa), "v"(pb) : "memory");
      if (__all(va[0] && va[1] && va[2] && va[3] &&
                vb[0] && vb[1] && vb[2] && vb[3])) break;
      __builtin_amdgcn_s_sleep(1);
    }
  };
  auto poll1 = [&](const unsigned int* pa) {
    for (;;) {
      i32x4 va;
      asm volatile("global_load_dwordx4 %0, %1, off sc0 sc1\n\ts_waitcnt vmcnt(0)"
                   : "=v"(va) : "v"(pa) : "memory");
      if (__all(va[0] && va[1] && va[2] && va[3])) break;
      __builtin_amdgcn_s_sleep(1);
    }
  };
  auto pollD = [&](const unsigned int* pa) {
    for (;;) {
      unsigned int v;
      asm volatile("global_load_dword %0, %1, off sc0 sc1\n\ts_waitcnt vmcnt(0)"
                   : "=v"(v) : "v"(pa) : "memory");
      if (__all(v != 0)) break;
      __builtin_amdgcn_s_sleep(1);
    }
  };

  if (bid < 160) {
    const int l = bid >> 5;
    const int wgi = bid & 31;
    const int K = (l == 0) ? 640 : 1024;
    const int nkit = K >> 5;
    const unsigned short* Wg = (l == 0) ? W0 : (l == 1) ? W1 : (l == 2) ? W2
                              : (l == 3) ? W3 : W4;
    const int row0 = wgi * 64;

    // one-time W fragment preload into LDS (8 waves)
    for (int mf = 0; mf < 4; ++mf)
      for (int kit = w; kit < nkit; kit += 8) {
        const s16x8 v = *reinterpret_cast<const s16x8*>(
            Wg + (size_t)(row0 + mf * 16 + l15) * K + kit * 32 + l4 * 8);
        *reinterpret_cast<s16x8*>(smem + ((mf * nkit + kit) << 10) + lane * 16) = v;
      }
    __syncthreads();

    float4 b4m[4];
    #pragma unroll
    for (int mf = 0; mf < 4; ++mf)
      b4m[mf] = *(const float4*)(bias + l * 2048 + row0 + mf * 16 + l4 * 4);

    float c_reg[4] = {0.f, 0.f, 0.f, 0.f};
    s16x8 bq[32];

    for (int t = 0; t < TT; ++t) {
      const int slotP = t & RINGM, slotM = (t + RINGM) & RINGM;
      const unsigned short* hin = (l > 0)
          ? hring + (size_t)((l - 1) * RING + slotP) * NBH : nullptr;
      const unsigned short* hown = hring + (size_t)(l * RING + slotM) * NBH;
      unsigned short* hout = hring + (size_t)(l * RING + slotP) * NBH;

      f32x4 acc[4] = {};
      s16x8 xb[4];

      if (l == 0) {
        #pragma unroll
        for (int kx = 0; kx < 4; ++kx) {
          const float* xs = x + ((size_t)(w * 16 + l15) * TT + t) * 128
                            + kx * 32 + l4 * 8;
          const float4 v0 = *(const float4*)xs;
          const float4 v1 = *(const float4*)(xs + 4);
          union { s16x8 v; unsigned short a[8]; } pk;
          pk.a[0] = f2bf(v0.x); pk.a[1] = f2bf(v0.y); pk.a[2] = f2bf(v0.z); pk.a[3] = f2bf(v0.w);
          pk.a[4] = f2bf(v1.x); pk.a[5] = f2bf(v1.y); pk.a[6] = f2bf(v1.z); pk.a[7] = f2bf(v1.w);
          xb[kx] = pk.v;
        }
      }

      // polls: self(t-1) + prev(t), 256 per-wave flags each, one x4 load per dep
      if (t > 0 || l > 0) {
        const unsigned int* pa = (t > 0) ? FLG(l, t - 1) + lane * 4
                                         : FLG(l - 1, t) + lane * 4;
        const unsigned int* pb = (l > 0) ? FLG(l - 1, t) + lane * 4 : pa;
        poll2(pa, pb);
      }
      if ((t & 3) == 0 && t >= 16) {
        if (l < 4) poll1(FLG(l + 1, t - 13) + lane * 4);
        else       pollD(FLG(5, t - 13) + (lane & 31));
      }

      const unsigned short* ppb = hown + ((size_t)l4 * 128 + w * 16 + l15) * 8;

      if (l == 0) {
        ISSUE16(0, ppb)          // slots 0..15 = hown kits (A kits 4..19)
        #pragma unroll
        for (int kx = 0; kx < 4; ++kx) {
          const s16x8 a0 = LDSA(0, kx), a1 = LDSA(1, kx), a2 = LDSA(2, kx), a3 = LDSA(3, kx);
          acc[0] = MFM(a0, xb[kx], acc[0]);
          acc[1] = MFM(a1, xb[kx], acc[1]);
          acc[2] = MFM(a2, xb[kx], acc[2]);
          acc[3] = MFM(a3, xb[kx], acc[3]);
        }
        C8(0, 4, "15")   C8(1, 5, "14")   C8(2, 6, "13")   C8(3, 7, "12")
        C8(4, 8, "11")   C8(5, 9, "10")   C8(6, 10, "9")   C8(7, 11, "8")
        C8(8, 12, "7")   C8(9, 13, "6")   C8(10, 14, "5")  C8(11, 15, "4")
        C8(12, 16, "3")  C8(13, 17, "2")  C8(14, 18, "1")  C8(15, 19, "0")
      } else {
        const unsigned short* qpb = hin + ((size_t)l4 * 128 + w * 16 + l15) * 8;
        ISSUE16(0, qpb)          // slots 0..15  = hin kits  (A kits 0..15)
        ISSUE16(16, ppb)         // slots 16..31 = hown kits (A kits 16..31)
        C8(0, 0, "31")   C8(1, 1, "30")   C8(2, 2, "29")   C8(3, 3, "28")
        C8(4, 4, "27")   C8(5, 5, "26")   C8(6, 6, "25")   C8(7, 7, "24")
        C8(8, 8, "23")   C8(9, 9, "22")   C8(10, 10, "21") C8(11, 11, "20")
        C8(12, 12, "19") C8(13, 13, "18") C8(14, 14, "17") C8(15, 15, "16")
        C8(16, 16, "15") C8(17, 17, "14") C8(18, 18, "13") C8(19, 19, "12")
        C8(20, 20, "11") C8(21, 21, "10") C8(22, 22, "9")  C8(23, 23, "8")
        C8(24, 24, "7")  C8(25, 25, "6")  C8(26, 26, "5")  C8(27, 27, "4")
        C8(28, 28, "3")  C8(29, 29, "2")  C8(30, 30, "1")  C8(31, 31, "0")
      }

      // epilogue: per-lane unit u = wgi*16 + mf*4 + l4, batch b = w*16 + l15.
      // Direct coalesced 2B stores (k-major: one instr spans <=2 lines).
      #pragma unroll
      for (int mf = 0; mf < 4; ++mf) {
        const float gi = acc[mf][0] + b4m[mf].x;
        const float gf = acc[mf][1] + b4m[mf].y;
        const float gg = acc[mf][2] + b4m[mf].z;
        const float go = acc[mf][3] + b4m[mf].w;
        const float cn = sigm(gf) * c_reg[mf] + sigm(gi) * tanhfast(gg);
        c_reg[mf] = cn;
        const unsigned int hv = f2bf(sigm(go) * tanhfast(cn));
        const unsigned short* ha = hout
            + ((size_t)(wgi * 2 + (mf >> 1)) * 128 + w * 16 + l15) * 8
            + (mf & 1) * 4 + l4;
        asm volatile("global_store_short %0, %1, off sc0 sc1"
                     :: "v"(ha), "v"(hv) : "memory");
      }
      asm volatile("s_waitcnt vmcnt(0)" ::: "memory");
      if (lane == 0) {
        const unsigned int* fa = FLG(l, t) + wgi * 8 + w;
        asm volatile("global_store_dword %0, %1, off sc0 sc1" :: "v"(fa), "v"(1u) : "memory");
      }
    }
  } else if (bid < 168) {
    // ---------------- projection (waves 0..3 active) ----------------
    if (w >= 4) { __syncthreads(); return; }
    const int wgp = bid - 160;
    const int b0 = wgp * 16;
    for (int mf = 0; mf < 2; ++mf)
      for (int kit = 0; kit < 16; ++kit) {
        const s16x8 v = *reinterpret_cast<const s16x8*>(
            Woutb + (size_t)(w * 32 + mf * 16 + l15) * 512 + kit * 32 + l4 * 8);
        *reinterpret_cast<s16x8*>(smem + (((w * 2 + mf) * 16 + kit) << 10) + lane * 16) = v;
      }
    __syncthreads();
    float4 bo[2];
    #pragma unroll
    for (int mf = 0; mf < 2; ++mf)
      bo[mf] = *(const float4*)(boutp + w * 32 + mf * 16 + l4 * 4);

    s16x8 brp[16];
    for (int t = 0; t < TT; ++t) {
      poll1(FLG(4, t) + lane * 4);
      const unsigned short* h4 = hring + (size_t)(4 * RING + (t & RINGM)) * NBH;
      const unsigned short* hbK = h4 + ((size_t)l4 * 128 + b0 + l15) * 8;
      GLD1P(brp[0], hbK)           GLD1P(brp[1], hbK + 4096)
      GLD1P(brp[2], hbK + 8192)    GLD1P(brp[3], hbK + 12288)
      GLD1P(brp[4], hbK + 16384)   GLD1P(brp[5], hbK + 20480)
      GLD1P(brp[6], hbK + 24576)   GLD1P(brp[7], hbK + 28672)
      GLD1P(brp[8], hbK + 32768)   GLD1P(brp[9], hbK + 36864)
      GLD1P(brp[10], hbK + 40960)  GLD1P(brp[11], hbK + 45056)
      GLD1P(brp[12], hbK + 49152)  GLD1P(brp[13], hbK + 53248)
      GLD1P(brp[14], hbK + 57344)  GLD1P(brp[15], hbK + 61440)
      f32x4 acc2[2] = {};
      #define PCON(Q, VM)                                                        \
        {                                                                        \
          BW1(brp[Q], VM);                                                       \
          const s16x8 a0 = *reinterpret_cast<const s16x8*>(                      \
              smem + (((w * 2 + 0) * 16 + Q) << 10) + lane * 16);                \
          const s16x8 a1 = *reinterpret_cast<const s16x8*>(                      \
              smem + (((w * 2 + 1) * 16 + Q) << 10) + lane * 16);                \
          acc2[0] = MFM(a0, brp[Q], acc2[0]);                                    \
          acc2[1] = MFM(a1, brp[Q], acc2[1]);                                    \
        }
      PCON(0, "15")  PCON(1, "14")  PCON(2, "13")  PCON(3, "12")
      PCON(4, "11")  PCON(5, "10")  PCON(6, "9")   PCON(7, "8")
      PCON(8, "7")   PCON(9, "6")   PCON(10, "5")  PCON(11, "4")
      PCON(12, "3")  PCON(13, "2")  PCON(14, "1")  PCON(15, "0")
      #pragma unroll
      for (int mf = 0; mf < 2; ++mf) {
        const int d0 = w * 32 + mf * 16 + l4 * 4;
        float4 r;
        r.x = acc2[mf][0] + bo[mf].x;
        r.y = acc2[mf][1] + bo[mf].y;
        r.z = acc2[mf][2] + bo[mf].z;
        r.w = acc2[mf][3] + bo[mf].w;
        *(float4*)(outp + ((size_t)(b0 + l15) * TT + t) * 128 + d0) = r;
      }
      asm volatile("s_waitcnt vmcnt(0)" ::: "memory");
      if (lane == 0) {
        const unsigned int* fa = FLG(5, t) + wgp * 4 + w;
        asm volatile("global_store_dword %0, %1, off sc0 sc1" :: "v"(fa), "v"(1u) : "memory");
      }
    }
  }
}

extern "C" void kernel_launch(void* const* d_in, const int* in_sizes, int n_in,
                              void* d_out, int out_size, void* d_ws, size_t ws_size,
                              hipStream_t stream) {
  (void)in_sizes; (void)n_in; (void)out_size; (void)ws_size;
  const float* x     = (const float*)d_in[0];
  const float* Wih1  = (const float*)d_in[1];
  const float* Whh1  = (const float*)d_in[2];
  const float* bih1  = (const float*)d_in[3];
  const float* bhh1  = (const float*)d_in[4];
  const float* Wih_r = (const float*)d_in[5];
  const float* Whh_r = (const float*)d_in[6];
  const float* bih_r = (const float*)d_in[7];
  const float* bhh_r = (const float*)d_in[8];
  const float* Wout  = (const float*)d_in[9];
  const float* boutp = (const float*)d_in[10];

  char* ws = (char*)d_ws;
  const size_t o_W0   = 0;
  const size_t o_W1   = o_W0 + 2048ull * 640 * 2;
  const size_t o_W2   = o_W1 + 2048ull * 1024 * 2;
  const size_t o_W3   = o_W2 + 2048ull * 1024 * 2;
  const size_t o_W4   = o_W3 + 2048ull * 1024 * 2;
  const size_t o_Wout = o_W4 + 2048ull * 1024 * 2;
  const size_t o_bias = o_Wout + 128ull * 512 * 2;
  const size_t o_ring = o_bias + 5ull * 2048 * 4;
  const size_t o_flag = o_ring + 5ull * RING * NBH * 2;
  const size_t o_end  = o_flag + 6ull * TT * 256 * 4;

  unsigned short* W0b  = (unsigned short*)(ws + o_W0);
  unsigned short* W1b  = (unsigned short*)(ws + o_W1);
  unsigned short* W2b  = (unsigned short*)(ws + o_W2);
  unsigned short* W3b  = (unsigned short*)(ws + o_W3);
  unsigned short* W4b  = (unsigned short*)(ws + o_W4);
  unsigned short* Wob  = (unsigned short*)(ws + o_Wout);
  float*          bias = (float*)(ws + o_bias);
  unsigned short* hrg  = (unsigned short*)(ws + o_ring);
  unsigned int*   flg  = (unsigned int*)(ws + o_flag);

  hipMemsetAsync(ws + o_ring, 0, o_end - o_ring, stream);

  convW<<<1024, 256, 0, stream>>>(Wih1, Whh1, bih1, bhh1, W0b, bias, 128, 512);
  for (int l = 1; l <= 4; ++l) {
    unsigned short* Wd = (l == 1) ? W1b : (l == 2) ? W2b : (l == 3) ? W3b : W4b;
    convW<<<1024, 256, 0, stream>>>(Wih_r + (size_t)(l - 1) * 2048 * 512,
                                    Whh_r + (size_t)(l - 1) * 2048 * 512,
                                    bih_r + (size_t)(l - 1) * 2048,
                                    bhh_r + (size_t)(l - 1) * 2048,
                                    Wd, bias + l * 2048, 512, 512);
  }
  convO<<<64, 256, 0, stream>>>(Wout, Wob);

  hipFuncSetAttribute((const void*)lstm_w8,
                      hipFuncAttributeMaxDynamicSharedMemorySize, 160 * 1024);

  lstm_w8<<<168, 512, 131072, stream>>>(x, W0b, W1b, W2b, W3b, W4b, Wob,
                                        bias, hrg, flg, boutp, (float*)d_out);
}